// Round 10
// baseline (383.986 us; speedup 1.0000x reference)
//
#include <hip/hip_runtime.h>
#include <stdint.h>

// Problem constants (fp32 everywhere)
#define NPOS 2394          // 38*63
#define CIN 512
#define KK 4608            // 512*9
#define NANCH 21546        // NPOS*9
#define PRE 6000
#define POST 300
#define NWORD 94           // ceil(6000/64)
#define NQ 8
#define QLEN 2694          // ceil(21546/8)
#define FEATT_BYTES 4902912   // NPOS*512*4

// ---- d_out scratch map (bytes). out bytes = 30,105,600.
// Conv-stage live set (packed tight to fit 3 P planes):
#define OFF_BH    0                  // fp16 weight hi [512][4608] = 4,718,592
#define OFF_BL    4718592            // fp16 weight lo            -> 9,437,184
#define OFF_FPH   9437184            // fp16 feat hi [41][65][512] = 2,728,960 -> 12,166,144
#define OFF_FPL   12166144           //                            -> 14,895,104
#define OFF_P0    14895104           // fp32 [2394][512] = 4,902,912 -> 19,798,016
#define OFF_P1    19798016           //                              -> 24,700,928
#define OFF_P2    24700928           //                              -> 29,603,840
// Post-conv stage aliases (old BH/BL/FP regions are dead):
#define OFF_KEYS  0                  // u64[21546]  = 172,368
#define OFF_PROP  180224             // f32[21546][4] = 344,736 -> 524,960
#define OFF_RPART 532480             // u32[21546][8] = 689,472 -> 1,221,952
#define OFF_SBOX  1228800            // f32[6000][4] = 96,000  -> 1,324,800
#define OFF_DIAG  1335296            // u64[6144][4] = 196,608 -> 1,531,904
#define OFF_MASK  4718592            // u64[6000][94] = 4,512,000 -> 9,230,592 (old BL)

#define NBORDER 138752               // 271 border cells * 512 ch of the padded plane

typedef _Float16 half8 __attribute__((ext_vector_type(8)));
typedef float f32x4 __attribute__((ext_vector_type(4)));

__device__ __forceinline__ void gload16(const void* g, void* l) {
    __builtin_amdgcn_global_load_lds((const __attribute__((address_space(1))) void*)g,
                                     (__attribute__((address_space(3))) void*)l, 16, 0, 0);
}

// wave-uniform 64-bit readlane (v_readlane_b32 x2)
__device__ __forceinline__ unsigned long long rl64(unsigned long long v, int l) {
    union { unsigned long long q; unsigned int d[2]; } s; s.q = v;
    unsigned int lo = __builtin_amdgcn_readlane(s.d[0], l);
    unsigned int hi = __builtin_amdgcn_readlane(s.d[1], l);
    return ((unsigned long long)hi << 32) | (unsigned long long)lo;
}

// anchor a wave-uniform u64 in SGPRs (forces SALU ops on it downstream)
__device__ __forceinline__ unsigned long long sgpr64(unsigned long long v) {
    union { unsigned long long q; unsigned int d[2]; } s; s.q = v;
    s.d[0] = __builtin_amdgcn_readfirstlane(s.d[0]);
    s.d[1] = __builtin_amdgcn_readfirstlane(s.d[1]);
    return s.q;
}

// FUSED preprocessing kernel.
// Blocks [0,1200): fp32 (2394,512) transpose of net + fp16 hi/lo split planes
//   (interior of padded [41][65][512] layout), scale 16 (exact pow2).
// Blocks [1200,1200+9216): w_rpn (co,ci,3,3) -> fp16 hi/lo [co][p*512+ci], scale 128.
// Blocks [1200+9216, 1200+9759): zero-fill the 271 border cells of the padded planes.
__global__ __launch_bounds__(256) void k_prep_all(const float* __restrict__ in,
                                                  const float* __restrict__ w,
                                                  float* __restrict__ featT,
                                                  _Float16* __restrict__ FPH,
                                                  _Float16* __restrict__ FPL,
                                                  _Float16* __restrict__ BH,
                                                  _Float16* __restrict__ BL) {
    int blk = blockIdx.x;
    if (blk < 1200) {
        __shared__ float tl[32][33];
        int tx = threadIdx.x & 31, tg = threadIdx.x >> 5;     // 32 x 8
        int posBase = (blk % 75) * 32, ciBase = (blk / 75) * 32;
#pragma unroll
        for (int j = 0; j < 4; ++j) {
            int ci = ciBase + tg + j * 8;
            int pos = posBase + tx;
            tl[tg + j * 8][tx] = (pos < NPOS) ? in[(size_t)ci * NPOS + pos] : 0.f;
        }
        __syncthreads();
#pragma unroll
        for (int j = 0; j < 4; ++j) {
            int pos = posBase + tg + j * 8;
            int ci = ciBase + tx;
            if (pos < NPOS) {
                float v = tl[tx][tg + j * 8];
                featT[(size_t)pos * 512 + ci] = v;
                int h = pos / 63, wq = pos - h * 63;
                int o = ((h + 1) * 65 + (wq + 1)) * 512 + ci;
                float a = v * 16.f;
                _Float16 ah = (_Float16)a;
                FPH[o] = ah;
                FPL[o] = (_Float16)(a - (float)ah);
            }
        }
        return;
    }
    int b = blk - 1200;
    if (b >= 9216) {
        int i2 = (b - 9216) * 256 + threadIdx.x;
        if (i2 < NBORDER) {
            int bi = i2 >> 9, ci = i2 & 511;
            int hp, wp;
            if (bi < 195) {
                hp = (bi < 65) ? 0 : ((bi < 130) ? 39 : 40);
                wp = (bi < 65) ? bi : ((bi < 130) ? bi - 65 : bi - 130);
            } else {
                int j = bi - 195;                  // 0..75
                hp = 1 + (j >> 1);
                wp = (j & 1) ? 64 : 0;
            }
            int o = (hp * 65 + wp) * 512 + ci;
            FPH[o] = (_Float16)0.f; FPL[o] = (_Float16)0.f;
        }
        return;
    }
    int idx = b * 256 + threadIdx.x;   // 512*4608 = 2,359,296 exact
    int co = idx / KK;
    int rem = idx - co * KK;
    int p = rem >> 9;
    int ci = rem & 511;
    float bv = w[(co * CIN + ci) * 9 + p] * 128.f;
    _Float16 bh = (_Float16)bv;
    _Float16 bl = (_Float16)(bv - (float)bh);
    BH[idx] = bh; BL[idx] = bl;
}

// 3x3 SAME conv as implicit-im2col split-fp16 MFMA GEMM.
// C = [(AH+AL)(BH+BL)]/2048, keeping AH*BH + AH*BL + AL*BH.
// Tile: 128 pos x 64 co, BK=64, 4 waves, split-K=3 (z covers taps 3z..3z+2).
// Grid: flat 456 = 8 XCD x 57, bijective XCD swizzle.
__global__ __launch_bounds__(256, 3) void k_conv3_mfma(
    const _Float16* __restrict__ FPH, const _Float16* __restrict__ FPL,
    const _Float16* __restrict__ BHp, const _Float16* __restrict__ BLp,
    float* __restrict__ P0, float* __restrict__ P1, float* __restrict__ P2)
{
    __shared__ __align__(16) char lds[49152];
    const int t = threadIdx.x;
    const int wave = t >> 6, lane = t & 63;

    const int bid = blockIdx.x;
    const int swz = (bid & 7) * 57 + (bid >> 3);
    const int z = swz / 152;                 // 152 = 8 co-blocks * 19 pos-blocks
    const int rem = swz - z * 152;
    const int coB = rem / 19;
    const int posB = rem - coB * 19;
    const int posBase = posB * 128;
    const int coBase  = coB * 64;
    float* __restrict__ P = (z == 0) ? P0 : ((z == 1) ? P1 : P2);

    const int wm = wave >> 1, wn = wave & 1;
    const int lr = lane & 15, lg = lane >> 4;

    int addrA[4][2], addrB[2][2];
#pragma unroll
    for (int m = 0; m < 4; ++m) {
        int row = wm * 64 + m * 16 + lr;
        int x = row & 7;
        addrA[m][0] = row * 128 + ((lg ^ x) << 4);
        addrA[m][1] = row * 128 + (((4 + lg) ^ x) << 4);
    }
#pragma unroll
    for (int n = 0; n < 2; ++n) {
        int row = wn * 32 + n * 16 + lr;
        int x = row & 7;
        addrB[n][0] = 32768 + row * 128 + ((lg ^ x) << 4);
        addrB[n][1] = 32768 + row * 128 + (((4 + lg) ^ x) << 4);
    }

    int baseA[4], ldsAo[4];
#pragma unroll
    for (int s = 0; s < 4; ++s) {
        int row = (wave * 4 + s) * 8 + (lane >> 3);
        int pos = posBase + row;
        int h = pos / 63;
        int w = pos - h * 63;
        int swzb = ((lane & 7) ^ (row & 7)) * 8;
        baseA[s] = (h * 65 + w) * 512 + swzb;
        ldsAo[s] = (wave * 4 + s) * 1024 + lane * 16;
    }
    int baseB[2], ldsBo[2];
#pragma unroll
    for (int s = 0; s < 2; ++s) {
        int row = (wave * 2 + s) * 8 + (lane >> 3);
        int swzb = ((lane & 7) ^ (row & 7)) * 8;
        baseB[s] = (coBase + row) * KK + swzb;
        ldsBo[s] = 32768 + (wave * 2 + s) * 1024 + lane * 16;
    }

    f32x4 acc[4][2];
#pragma unroll
    for (int m = 0; m < 4; ++m)
#pragma unroll
        for (int n = 0; n < 2; ++n) acc[m][n] = (f32x4){0.f, 0.f, 0.f, 0.f};

    const int kbeg = z * 1536;
    for (int step = 0; step < 24; ++step) {
        int k0 = kbeg + step * 64;
        int p = k0 >> 9;
        int ci0 = k0 & 511;
        int kh = p / 3;
        int kw = p - kh * 3;
        int dA = (kh * 65 + kw) * 512 + ci0;
#pragma unroll
        for (int s = 0; s < 4; ++s) {
            int so = baseA[s] + dA;
            gload16(FPH + so, lds + ldsAo[s]);
            gload16(FPL + so, lds + 16384 + ldsAo[s]);
        }
#pragma unroll
        for (int s = 0; s < 2; ++s) {
            int so = baseB[s] + k0;
            gload16(BHp + so, lds + ldsBo[s]);
            gload16(BLp + so, lds + 8192 + ldsBo[s]);
        }
        __syncthreads();
#pragma unroll
        for (int ks = 0; ks < 2; ++ks) {
            half8 aH[4], aL[4], bH[2], bL[2];
#pragma unroll
            for (int m = 0; m < 4; ++m) {
                aH[m] = *(const half8*)(lds + addrA[m][ks]);
                aL[m] = *(const half8*)(lds + 16384 + addrA[m][ks]);
            }
#pragma unroll
            for (int n = 0; n < 2; ++n) {
                bH[n] = *(const half8*)(lds + addrB[n][ks]);
                bL[n] = *(const half8*)(lds + 8192 + addrB[n][ks]);
            }
#pragma unroll
            for (int m = 0; m < 4; ++m)
#pragma unroll
                for (int n = 0; n < 2; ++n) {
                    acc[m][n] = __builtin_amdgcn_mfma_f32_16x16x32_f16(aH[m], bH[n], acc[m][n], 0, 0, 0);
                    acc[m][n] = __builtin_amdgcn_mfma_f32_16x16x32_f16(aH[m], bL[n], acc[m][n], 0, 0, 0);
                    acc[m][n] = __builtin_amdgcn_mfma_f32_16x16x32_f16(aL[m], bH[n], acc[m][n], 0, 0, 0);
                }
        }
        __syncthreads();
    }

#pragma unroll
    for (int m = 0; m < 4; ++m) {
        int pbase = posBase + wm * 64 + m * 16 + lg * 4;
        int co = coBase + wn * 32 + lr;
#pragma unroll
        for (int r = 0; r < 4; ++r) {
            int pos = pbase + r;
            if (pos < NPOS) {
                P[(size_t)pos * 512 + co]      = acc[m][0][r] * (1.f / 2048.f);
                P[(size_t)pos * 512 + co + 16] = acc[m][1][r] * (1.f / 2048.f);
            }
        }
    }
}

// 1x1 heads (fuses conv bias+ReLU over P0+P1+P2) + softmax-prob + decode + clip + key.
__global__ __launch_bounds__(256) void k_heads(const float* __restrict__ P0,
                                               const float* __restrict__ P1,
                                               const float* __restrict__ P2,
                                               const float* __restrict__ brpn,
                                               const float* __restrict__ wcls,
                                               const float* __restrict__ bcls,
                                               const float* __restrict__ wbbox,
                                               const float* __restrict__ bbbox,
                                               const float* __restrict__ anchors,
                                               float* __restrict__ proposals,
                                               unsigned long long* __restrict__ keys) {
    __shared__ float x[512];
    __shared__ float part[54][4];
    __shared__ float logit[54];
    int pos = blockIdx.x;
    int t = threadIdx.x;
    {
        size_t o = (size_t)pos * 512 + t;
        float v0 = P0[o] + P1[o] + P2[o] + brpn[t];
        float v1 = P0[o + 256] + P1[o + 256] + P2[o + 256] + brpn[t + 256];
        x[t] = v0 > 0.f ? v0 : 0.f;
        x[t + 256] = v1 > 0.f ? v1 : 0.f;
    }
    __syncthreads();
    if (t < 216) {
        int o = t >> 2, q = t & 3;
        const float* wr = (o < 18) ? (wcls + o * 512) : (wbbox + (o - 18) * 512);
        float s = 0.f;
        int base = q * 128;
#pragma unroll 4
        for (int k2 = 0; k2 < 128; ++k2) s += x[base + k2] * wr[base + k2];
        part[o][q] = s;
    }
    __syncthreads();
    if (t < 54) {
        float b = (t < 18) ? bcls[t] : bbbox[t - 18];
        logit[t] = part[t][0] + part[t][1] + part[t][2] + part[t][3] + b;
    }
    __syncthreads();
    if (t < 9) {
        int a = t;
        float bg = logit[a], fg = logit[9 + a];
        float score = 1.f / (1.f + expf(bg - fg));
        float dx = logit[18 + 4 * a], dy = logit[19 + 4 * a];
        float dw = logit[20 + 4 * a], dh = logit[21 + 4 * a];
        int idx = pos * 9 + a;
        float ax1 = anchors[idx * 4 + 0], ay1 = anchors[idx * 4 + 1];
        float ax2 = anchors[idx * 4 + 2], ay2 = anchors[idx * 4 + 3];
        float aw = ax2 - ax1 + 1.f, ah = ay2 - ay1 + 1.f;
        float cx = ax1 + 0.5f * aw, cy = ay1 + 0.5f * ah;
        float pcx = dx * aw + cx, pcy = dy * ah + cy;
        float pw = expf(dw) * aw, ph = expf(dh) * ah;
        float x1 = fminf(fmaxf(pcx - 0.5f * pw, 0.f), 999.f);
        float y1 = fminf(fmaxf(pcy - 0.5f * ph, 0.f), 599.f);
        float x2 = fminf(fmaxf(pcx + 0.5f * pw, 0.f), 999.f);
        float y2 = fminf(fmaxf(pcy + 0.5f * ph, 0.f), 599.f);
        proposals[idx * 4 + 0] = x1; proposals[idx * 4 + 1] = y1;
        proposals[idx * 4 + 2] = x2; proposals[idx * 4 + 3] = y2;
        union { float f; unsigned int i; } sv; sv.f = score;
        keys[idx] = (((unsigned long long)sv.i) << 32) |
                    (unsigned long long)(0xFFFFFFFFu - (unsigned)idx);
    }
}

__global__ __launch_bounds__(256) void k_rank_partial(const unsigned long long* __restrict__ keys,
                                                      unsigned int* __restrict__ rpart) {
    __shared__ unsigned long long kc[1024];
    int i = blockIdx.x * 256 + threadIdx.x;
    int q = blockIdx.y;
    unsigned long long myk = (i < NANCH) ? keys[i] : 0xFFFFFFFFFFFFFFFFull;
    int j0 = q * QLEN;
    int j1 = j0 + QLEN; if (j1 > NANCH) j1 = NANCH;
    unsigned int cnt = 0;
    for (int base = j0; base < j1; base += 1024) {
        int nload = j1 - base; if (nload > 1024) nload = 1024;
        __syncthreads();
        for (int u = threadIdx.x; u < 1024; u += 256)
            kc[u] = (base + u < j1) ? keys[base + u] : 0ull;
        __syncthreads();
        for (int u = 0; u < nload; ++u)
            cnt += (kc[u] > myk) ? 1u : 0u;
    }
    if (i < NANCH) rpart[i * NQ + q] = cnt;
}

// Ranks are a permutation of 0..NANCH-1 (keys unique via idx tiebreak), so all
// PRE slots get written -> no zero-init of sboxes needed.
__global__ void k_rank_scatter(const unsigned int* __restrict__ rpart,
                               const float* __restrict__ proposals,
                               float* __restrict__ sboxes) {
    int i = blockIdx.x * 256 + threadIdx.x;
    if (i >= NANCH) return;
    unsigned int r = 0;
#pragma unroll
    for (int q = 0; q < NQ; q++) r += rpart[i * NQ + q];
    if (r < PRE) {
        sboxes[r * 4 + 0] = proposals[i * 4 + 0];
        sboxes[r * 4 + 1] = proposals[i * 4 + 1];
        sboxes[r * 4 + 2] = proposals[i * 4 + 2];
        sboxes[r * 4 + 3] = proposals[i * 4 + 3];
    }
}

// IoU mask. Also packs the per-candidate diagonal 4-word slice into diag4.
// diag4 padding rows (6000..6143) are never selected by the scan (valid mask),
// so they need no zero-init.
__global__ __launch_bounds__(64) void k_nms_mask(const float* __restrict__ sboxes,
                                                 unsigned long long* __restrict__ mask,
                                                 unsigned long long* __restrict__ diag4) {
    __shared__ float bx[64][5];   // pad: breaks 8-way write bank conflict
    int ib = blockIdx.x, jb = blockIdx.y;
    int lane = threadIdx.x;
    int j = jb * 64 + lane;
    if (j < PRE) {
        bx[lane][0] = sboxes[j * 4 + 0]; bx[lane][1] = sboxes[j * 4 + 1];
        bx[lane][2] = sboxes[j * 4 + 2]; bx[lane][3] = sboxes[j * 4 + 3];
    } else {
        bx[lane][0] = 3e8f; bx[lane][1] = 3e8f; bx[lane][2] = 3e8f; bx[lane][3] = 3e8f;
    }
    __syncthreads();
    int i = ib * 64 + lane;
    if (i >= PRE) return;
    float x1 = sboxes[i * 4 + 0], y1 = sboxes[i * 4 + 1];
    float x2 = sboxes[i * 4 + 2], y2 = sboxes[i * 4 + 3];
    float ar = (x2 - x1 + 1.f) * (y2 - y1 + 1.f);
    unsigned long long bits = 0;
#pragma unroll 4
    for (int u = 0; u < 64; u++) {
        int j2 = jb * 64 + u;
        float iw = fminf(x2, bx[u][2]) - fmaxf(x1, bx[u][0]) + 1.f;
        float ih = fminf(y2, bx[u][3]) - fmaxf(y1, bx[u][1]) + 1.f;
        iw = fmaxf(iw, 0.f); ih = fmaxf(ih, 0.f);
        float inter = iw * ih;
        float arj = (bx[u][2] - bx[u][0] + 1.f) * (bx[u][3] - bx[u][1] + 1.f);
        float iou = inter / (ar + arj - inter);
        if (iou > 0.7f && j2 > i) bits |= (1ull << u);
    }
    mask[(size_t)i * NWORD + jb] = bits;
    if ((jb >> 2) == (ib >> 2)) diag4[(size_t)i * 4 + (jb & 3)] = bits;
}

// Greedy scan, 256-wide superblocks, counted-vmcnt pipeline.
// Decision loop SCALARIZED: avail/cv/keptm anchored in SGPRs via readfirstlane
// so the serial chain runs on the SALU (s_ff1/s_andn2/s_lshl, 1-4cy) instead of
// VALU-latency chains. Incremental avail recurrence (no rm/valid/above rebuild).
// FUSED roi-gather epilogue. Bit-identical greedy order.
#define NSB 24
#define SBW 256
#define NSLOT 20
__global__ __launch_bounds__(64) void k_nms_scan(const unsigned long long* __restrict__ mask,
                                                 const unsigned long long* __restrict__ diag4,
                                                 const float* __restrict__ sboxes,
                                                 float* __restrict__ outF) {
    __shared__ __align__(16) unsigned long long tile[2][SBW * 4];   // 2 x 8KB
    __shared__ __align__(16) char ldsrow[NSLOT * 1024];             // kept-row slots
    __shared__ int ldsk[POST];
    const int lane = threadIdx.x;
    const char* dg = (const char*)diag4;

    for (int c = 0; c < 8; ++c)
        gload16(dg + c * 1024 + (size_t)lane * 16, (char*)tile[0] + c * 1024);

    unsigned long long rem0 = 0, rem1 = 0;   // lane l owns words l and 64+l
    int nk = 0, npend = 0;

    for (int sb = 0; sb < NSB; ++sb) {
        if (sb + 1 < NSB) {
            const char* src = dg + (size_t)(sb + 1) * 8192;
            char* dst = (char*)tile[(sb + 1) & 1];
            for (int c = 0; c < 8; ++c)
                gload16(src + c * 1024 + (size_t)lane * 16, dst + c * 1024);
            asm volatile("s_waitcnt vmcnt(8)" ::: "memory");
        } else {
            asm volatile("s_waitcnt vmcnt(0)" ::: "memory");
        }
        __builtin_amdgcn_sched_barrier(0);

        for (int q = 0; q < npend; ++q) {
            const unsigned long long* lr = (const unsigned long long*)(ldsrow + q * 1024);
            rem0 |= lr[lane];
            if (lane < NWORD - 64) rem1 |= lr[64 + lane];
        }
        npend = 0;

        const unsigned long long* tl = tile[sb & 1];
        unsigned long long d[4][4];
#pragma unroll
        for (int q = 0; q < 4; ++q) {
            ulonglong2 e0 = *(const ulonglong2*)&tl[(q * 64 + lane) * 4];
            ulonglong2 e1 = *(const ulonglong2*)&tl[(q * 64 + lane) * 4 + 2];
            d[q][0] = e0.x; d[q][1] = e0.y; d[q][2] = e1.x; d[q][3] = e1.y;
        }

        const int w0 = 4 * sb;
        const int base = sb * SBW;
        unsigned long long rmw[4];
#pragma unroll
        for (int j = 0; j < 4; ++j) {
            int w = w0 + j;
            rmw[j] = (w < 64) ? rl64(rem0, w) : ((w < NWORD) ? rl64(rem1, w - 64) : ~0ull);
        }

#pragma unroll
        for (int p = 0; p < 4; ++p) {
            int w = w0 + p;
            if (w >= NWORD) break;
            const unsigned long long valid = (w == NWORD - 1) ? ((1ull << 48) - 1) : ~0ull;
            // scalar incremental availability recurrence
            unsigned long long avail = sgpr64(~rmw[p] & valid);
            unsigned long long keptm = 0;
            while (avail) {
                int u = (int)(__ffsll((long long)avail) - 1);
                keptm |= 1ull << u;
                ++nk;
                if (nk == POST) break;
                unsigned long long cv = rl64(d[p][p], u);
                unsigned long long abv = (u == 63) ? 0ull : (~0ull << (u + 1));
                avail = avail & ~cv & abv;
            }
            keptm = sgpr64(keptm);
            // deferred forward-word merges (pipelined, off the decision chain)
            {
                unsigned long long bits = keptm;
                while (bits) {
                    int u = (int)(__ffsll((long long)bits) - 1); bits &= bits - 1;
#pragma unroll
                    for (int j = p + 1; j < 4; ++j) rmw[j] |= rl64(d[p][j], u);
                }
            }
            // record keep indices + batched row-load issue (off-chain)
            unsigned long long bits = keptm;
            int nkb = nk - __builtin_popcountll(keptm);
            while (bits) {
                int u = (int)(__ffsll((long long)bits) - 1); bits &= bits - 1;
                int i = base + p * 64 + u;
                if (lane == 0) ldsk[nkb] = i;
                ++nkb;
                if (npend == NSLOT) {
                    asm volatile("s_waitcnt vmcnt(0)" ::: "memory");
                    __builtin_amdgcn_sched_barrier(0);
                    for (int q = 0; q < NSLOT; ++q) {
                        const unsigned long long* lr = (const unsigned long long*)(ldsrow + q * 1024);
                        rem0 |= lr[lane];
                        if (lane < NWORD - 64) rem1 |= lr[64 + lane];
                    }
                    npend = 0;
                }
                gload16((const char*)(mask + (size_t)i * NWORD) + (size_t)lane * 16,
                        ldsrow + npend * 1024);
                ++npend;
            }
            if (nk >= POST) goto done;
        }
    }
done:
    asm volatile("s_waitcnt vmcnt(0)" ::: "memory");
    // fused gather: boxes -> regs (all loads fenced before any store, since
    // header stores alias the sboxes scratch region inside d_out)
    float4 bx[5];
#pragma unroll
    for (int i = 0; i < 5; ++i) {
        int r = lane + i * 64;
        if (r < POST) {
            int ki = (r < nk) ? ldsk[r] : PRE - 1;
            bx[i] = *reinterpret_cast<const float4*>(sboxes + ki * 4);
        }
    }
    asm volatile("s_waitcnt vmcnt(0)" ::: "memory");
    __builtin_amdgcn_sched_barrier(0);
#pragma unroll
    for (int i = 0; i < 5; ++i) {
        int r = lane + i * 64;
        if (r < POST) {
#pragma unroll
            for (int cg = 0; cg < 8; ++cg)
                *reinterpret_cast<float4*>(outF + (size_t)(r * 512 + cg * 64) * 49) = bx[i];
        }
    }
}

// FAST crop: coalesced featT reads (lane=channel) + LDS-staged coalesced writes.
__global__ __launch_bounds__(256) void k_crop_fast(const float* __restrict__ featT,
                                                   float* out) {
    __shared__ float lds[4][49 * 65];
    int r = blockIdx.x;
    int w = threadIdx.x >> 6, lane = threadIdx.x & 63;
    int cg = blockIdx.y * 4 + w;
    int c = cg * 64 + lane;
    float* chunk = out + (size_t)(r * 512 + cg * 64) * 49;
    const float4 b = *reinterpret_cast<const float4*>(chunk);
    float x1 = b.x, y1 = b.y, x2 = b.z, y2 = b.w;
    float by1 = (y1 / 16.f) / 37.f, bx1 = (x1 / 16.f) / 62.f;
    float by2 = (y2 / 16.f) / 37.f, bx2 = (x2 / 16.f) / 62.f;
    float dyn = by2 - by1, dxn = bx2 - bx1;
    for (int e = 0; e < 49; ++e) {
        int oy = e / 7, ox = e - oy * 7;
        float vv[4];
#pragma unroll
        for (int dy = 0; dy < 2; ++dy) {
            int sy = 2 * oy + dy;
            float ty = (float)sy / 13.f;
            float ys = by1 * 37.f + (ty * dyn) * 37.f;
            float yf = floorf(ys);
            float wy = ys - yf;
            int y0  = (int)fminf(fmaxf(yf, 0.f), 37.f);
            int y1i = (int)fminf(fmaxf(yf + 1.f, 0.f), 37.f);
#pragma unroll
            for (int dxx = 0; dxx < 2; ++dxx) {
                int sx = 2 * ox + dxx;
                float tx = (float)sx / 13.f;
                float xs = bx1 * 62.f + (tx * dxn) * 62.f;
                float xf = floorf(xs);
                float wx = xs - xf;
                int x0  = (int)fminf(fmaxf(xf, 0.f), 62.f);
                int x1i = (int)fminf(fmaxf(xf + 1.f, 0.f), 62.f);
                float f00 = featT[(size_t)(y0 * 63 + x0) * 512 + c];
                float f01 = featT[(size_t)(y0 * 63 + x1i) * 512 + c];
                float f10 = featT[(size_t)(y1i * 63 + x0) * 512 + c];
                float f11 = featT[(size_t)(y1i * 63 + x1i) * 512 + c];
                vv[dy * 2 + dxx] = f00 * (1.f - wy) * (1.f - wx) + f01 * (1.f - wy) * wx +
                                   f10 * wy * (1.f - wx) + f11 * wy * wx;
            }
        }
        lds[w][e * 65 + lane] = fmaxf(fmaxf(vv[0], vv[1]), fmaxf(vv[2], vv[3]));
    }
    __syncthreads();
    for (int i = lane; i < 64 * 49; i += 64) {
        int cl = i / 49, e = i - cl * 49;
        chunk[i] = lds[w][e * 65 + cl];
    }
}

// SLOW fallback crop (reads NCHW net) — used only if ws too small
__global__ __launch_bounds__(64) void k_crop_slow(const float* __restrict__ net,
                                                  float* out) {
    int r = blockIdx.x, cg = blockIdx.y;
    int lane = threadIdx.x;
    int c = cg * 64 + lane;
    const float4 b = *reinterpret_cast<const float4*>(out + (size_t)(r * 512 + cg * 64) * 49);
    float x1 = b.x, y1 = b.y, x2 = b.z, y2 = b.w;
    float by1 = (y1 / 16.f) / 37.f, bx1 = (x1 / 16.f) / 62.f;
    float by2 = (y2 / 16.f) / 37.f, bx2 = (x2 / 16.f) / 62.f;
    float dyn = by2 - by1, dxn = bx2 - bx1;
    const float* fc = net + (size_t)c * NPOS;
    float* orow = out + ((size_t)r * 512 + c) * 49;
    for (int e = 0; e < 49; ++e) {
        int oy = e / 7, ox = e - oy * 7;
        float vv[4];
#pragma unroll
        for (int dy = 0; dy < 2; ++dy) {
            int sy = 2 * oy + dy;
            float ty = (float)sy / 13.f;
            float ys = by1 * 37.f + (ty * dyn) * 37.f;
            float yf = floorf(ys);
            float wy = ys - yf;
            int y0  = (int)fminf(fmaxf(yf, 0.f), 37.f);
            int y1i = (int)fminf(fmaxf(yf + 1.f, 0.f), 37.f);
#pragma unroll
            for (int dxx = 0; dxx < 2; ++dxx) {
                int sx = 2 * ox + dxx;
                float tx = (float)sx / 13.f;
                float xs = bx1 * 62.f + (tx * dxn) * 62.f;
                float xf = floorf(xs);
                float wx = xs - xf;
                int x0  = (int)fminf(fmaxf(xf, 0.f), 62.f);
                int x1i = (int)fminf(fmaxf(xf + 1.f, 0.f), 62.f);
                float f00 = fc[y0 * 63 + x0];
                float f01 = fc[y0 * 63 + x1i];
                float f10 = fc[y1i * 63 + x0];
                float f11 = fc[y1i * 63 + x1i];
                vv[dy * 2 + dxx] = f00 * (1.f - wy) * (1.f - wx) + f01 * (1.f - wy) * wx +
                                   f10 * wy * (1.f - wx) + f11 * wy * wx;
            }
        }
        orow[e] = fmaxf(fmaxf(vv[0], vv[1]), fmaxf(vv[2], vv[3]));
    }
}

extern "C" void kernel_launch(void* const* d_in, const int* in_sizes, int n_in,
                              void* d_out, int out_size, void* d_ws, size_t ws_size,
                              hipStream_t stream) {
    auto find = [&](int count, int fallback) {
        for (int i = 0; i < n_in; ++i) if (in_sizes[i] == count) return i;
        return fallback;
    };
    const float* net   = (const float*)d_in[find(NPOS * CIN, 0)];
    const float* wrpn  = (const float*)d_in[find(512 * KK, 1)];
    const float* brpn  = (const float*)d_in[find(512, 2)];
    const float* wcls  = (const float*)d_in[find(18 * 512, 3)];
    const float* bcls  = (const float*)d_in[find(18, 4)];
    const float* wbbox = (const float*)d_in[find(36 * 512, 5)];
    const float* bbbox = (const float*)d_in[find(36, 6)];
    const float* anch  = (const float*)d_in[find(NANCH * 4, 7)];

    char* ob = (char*)d_out;
    _Float16* BH             = (_Float16*)(ob + OFF_BH);
    _Float16* BL             = (_Float16*)(ob + OFF_BL);
    _Float16* FPH            = (_Float16*)(ob + OFF_FPH);
    _Float16* FPL            = (_Float16*)(ob + OFF_FPL);
    float* P0                = (float*)(ob + OFF_P0);
    float* P1                = (float*)(ob + OFF_P1);
    float* P2                = (float*)(ob + OFF_P2);
    unsigned long long* keys = (unsigned long long*)(ob + OFF_KEYS);
    float* proposals         = (float*)(ob + OFF_PROP);
    unsigned int* rpart      = (unsigned int*)(ob + OFF_RPART);
    float* sboxes            = (float*)(ob + OFF_SBOX);
    unsigned long long* diag4= (unsigned long long*)(ob + OFF_DIAG);
    unsigned long long* mask = (unsigned long long*)(ob + OFF_MASK);
    float* outF              = (float*)d_out;

    // featT in d_ws if it fits (survives the output-overwriting crop -> fast path).
    // Fallback: alias dead-until-conv P0 region (crop_slow reads net instead).
    const bool ws_ok = (ws_size >= (size_t)FEATT_BYTES);
    float* featT = ws_ok ? (float*)d_ws : (float*)(ob + OFF_P0);

    hipLaunchKernelGGL(k_prep_all, dim3(1200 + 9216 + 543), dim3(256), 0, stream,
                       net, wrpn, featT, FPH, FPL, BH, BL);
    hipLaunchKernelGGL(k_conv3_mfma, dim3(456), dim3(256), 0, stream, FPH, FPL, BH, BL, P0, P1, P2);
    hipLaunchKernelGGL(k_heads, dim3(NPOS), dim3(256), 0, stream, P0, P1, P2, brpn, wcls, bcls, wbbox, bbbox, anch, proposals, keys);
    hipLaunchKernelGGL(k_rank_partial, dim3(85, NQ), dim3(256), 0, stream, keys, rpart);
    hipLaunchKernelGGL(k_rank_scatter, dim3(85), dim3(256), 0, stream, rpart, proposals, sboxes);
    hipLaunchKernelGGL(k_nms_mask, dim3(NWORD, NWORD), dim3(64), 0, stream, sboxes, mask, diag4);
    hipLaunchKernelGGL(k_nms_scan, dim3(1), dim3(64), 0, stream, mask, diag4, sboxes, outF);
    if (ws_ok)
        hipLaunchKernelGGL(k_crop_fast, dim3(POST, 2), dim3(256), 0, stream, featT, outF);
    else
        hipLaunchKernelGGL(k_crop_slow, dim3(POST, 8), dim3(64), 0, stream, net, outF);
}

// Round 11
// 380.627 us; speedup vs baseline: 1.0088x; 1.0088x over previous
//
#include <hip/hip_runtime.h>
#include <stdint.h>

// Problem constants (fp32 everywhere)
#define NPOS 2394          // 38*63
#define CIN 512
#define KK 4608            // 512*9
#define NANCH 21546        // NPOS*9
#define PRE 6000
#define POST 300
#define NWORD 94           // ceil(6000/64)
#define NQ 8
#define QLEN 2694          // ceil(21546/8)
#define FEATT_BYTES 4902912   // NPOS*512*4

// ---- d_out scratch map (bytes). out bytes = 30,105,600.
// Conv-stage live set (packed tight to fit 3 P planes):
#define OFF_BH    0                  // fp16 weight hi [512][4608] = 4,718,592
#define OFF_BL    4718592            // fp16 weight lo            -> 9,437,184
#define OFF_FPH   9437184            // fp16 feat hi [41][65][512] = 2,728,960 -> 12,166,144
#define OFF_FPL   12166144           //                            -> 14,895,104
#define OFF_P0    14895104           // fp32 [2394][512] = 4,902,912 -> 19,798,016
#define OFF_P1    19798016           //                              -> 24,700,928
#define OFF_P2    24700928           //                              -> 29,603,840
// Post-conv stage aliases (old BH/BL/FP regions are dead):
#define OFF_KEYS  0                  // u64[21546]  = 172,368
#define OFF_PROP  180224             // f32[21546][4] = 344,736 -> 524,960
#define OFF_RPART 532480             // u32[21546][8] = 689,472 -> 1,221,952
#define OFF_SBOX  1228800            // f32[6000][4] = 96,000  -> 1,324,800
#define OFF_DIAG  1335296            // u64[6144][4] = 196,608 -> 1,531,904
#define OFF_MASK  4718592            // u64[6000][94] = 4,512,000 -> 9,230,592 (old BL)

#define NBORDER 138752               // 271 border cells * 512 ch of the padded plane

typedef _Float16 half8 __attribute__((ext_vector_type(8)));
typedef float f32x4 __attribute__((ext_vector_type(4)));

__device__ __forceinline__ void gload16(const void* g, void* l) {
    __builtin_amdgcn_global_load_lds((const __attribute__((address_space(1))) void*)g,
                                     (__attribute__((address_space(3))) void*)l, 16, 0, 0);
}

// wave-uniform 64-bit readlane (v_readlane_b32 x2)
__device__ __forceinline__ unsigned long long rl64(unsigned long long v, int l) {
    union { unsigned long long q; unsigned int d[2]; } s; s.q = v;
    unsigned int lo = __builtin_amdgcn_readlane(s.d[0], l);
    unsigned int hi = __builtin_amdgcn_readlane(s.d[1], l);
    return ((unsigned long long)hi << 32) | (unsigned long long)lo;
}

// FUSED preprocessing kernel.
// Blocks [0,1200): fp32 (2394,512) transpose of net + fp16 hi/lo split planes
//   (interior of padded [41][65][512] layout), scale 16 (exact pow2).
// Blocks [1200,1200+9216): w_rpn (co,ci,3,3) -> fp16 hi/lo [co][p*512+ci], scale 128.
// Blocks [1200+9216, 1200+9759): zero-fill the 271 border cells of the padded planes.
__global__ __launch_bounds__(256) void k_prep_all(const float* __restrict__ in,
                                                  const float* __restrict__ w,
                                                  float* __restrict__ featT,
                                                  _Float16* __restrict__ FPH,
                                                  _Float16* __restrict__ FPL,
                                                  _Float16* __restrict__ BH,
                                                  _Float16* __restrict__ BL) {
    int blk = blockIdx.x;
    if (blk < 1200) {
        __shared__ float tl[32][33];
        int tx = threadIdx.x & 31, tg = threadIdx.x >> 5;     // 32 x 8
        int posBase = (blk % 75) * 32, ciBase = (blk / 75) * 32;
#pragma unroll
        for (int j = 0; j < 4; ++j) {
            int ci = ciBase + tg + j * 8;
            int pos = posBase + tx;
            tl[tg + j * 8][tx] = (pos < NPOS) ? in[(size_t)ci * NPOS + pos] : 0.f;
        }
        __syncthreads();
#pragma unroll
        for (int j = 0; j < 4; ++j) {
            int pos = posBase + tg + j * 8;
            int ci = ciBase + tx;
            if (pos < NPOS) {
                float v = tl[tx][tg + j * 8];
                featT[(size_t)pos * 512 + ci] = v;
                int h = pos / 63, wq = pos - h * 63;
                int o = ((h + 1) * 65 + (wq + 1)) * 512 + ci;
                float a = v * 16.f;
                _Float16 ah = (_Float16)a;
                FPH[o] = ah;
                FPL[o] = (_Float16)(a - (float)ah);
            }
        }
        return;
    }
    int b = blk - 1200;
    if (b >= 9216) {
        int i2 = (b - 9216) * 256 + threadIdx.x;
        if (i2 < NBORDER) {
            int bi = i2 >> 9, ci = i2 & 511;
            int hp, wp;
            if (bi < 195) {
                hp = (bi < 65) ? 0 : ((bi < 130) ? 39 : 40);
                wp = (bi < 65) ? bi : ((bi < 130) ? bi - 65 : bi - 130);
            } else {
                int j = bi - 195;                  // 0..75
                hp = 1 + (j >> 1);
                wp = (j & 1) ? 64 : 0;
            }
            int o = (hp * 65 + wp) * 512 + ci;
            FPH[o] = (_Float16)0.f; FPL[o] = (_Float16)0.f;
        }
        return;
    }
    int idx = b * 256 + threadIdx.x;   // 512*4608 = 2,359,296 exact
    int co = idx / KK;
    int rem = idx - co * KK;
    int p = rem >> 9;
    int ci = rem & 511;
    float bv = w[(co * CIN + ci) * 9 + p] * 128.f;
    _Float16 bh = (_Float16)bv;
    _Float16 bl = (_Float16)(bv - (float)bh);
    BH[idx] = bh; BL[idx] = bl;
}

// 3x3 SAME conv as implicit-im2col split-fp16 MFMA GEMM.
// C = [(AH+AL)(BH+BL)]/2048, keeping AH*BH + AH*BL + AL*BH.
// Tile: 128 pos x 64 co, BK=64, 4 waves, split-K=3 (z covers taps 3z..3z+2).
// Grid: flat 456 = 8 XCD x 57, bijective XCD swizzle.
__global__ __launch_bounds__(256, 3) void k_conv3_mfma(
    const _Float16* __restrict__ FPH, const _Float16* __restrict__ FPL,
    const _Float16* __restrict__ BHp, const _Float16* __restrict__ BLp,
    float* __restrict__ P0, float* __restrict__ P1, float* __restrict__ P2)
{
    __shared__ __align__(16) char lds[49152];
    const int t = threadIdx.x;
    const int wave = t >> 6, lane = t & 63;

    const int bid = blockIdx.x;
    const int swz = (bid & 7) * 57 + (bid >> 3);
    const int z = swz / 152;                 // 152 = 8 co-blocks * 19 pos-blocks
    const int rem = swz - z * 152;
    const int coB = rem / 19;
    const int posB = rem - coB * 19;
    const int posBase = posB * 128;
    const int coBase  = coB * 64;
    float* __restrict__ P = (z == 0) ? P0 : ((z == 1) ? P1 : P2);

    const int wm = wave >> 1, wn = wave & 1;
    const int lr = lane & 15, lg = lane >> 4;

    int addrA[4][2], addrB[2][2];
#pragma unroll
    for (int m = 0; m < 4; ++m) {
        int row = wm * 64 + m * 16 + lr;
        int x = row & 7;
        addrA[m][0] = row * 128 + ((lg ^ x) << 4);
        addrA[m][1] = row * 128 + (((4 + lg) ^ x) << 4);
    }
#pragma unroll
    for (int n = 0; n < 2; ++n) {
        int row = wn * 32 + n * 16 + lr;
        int x = row & 7;
        addrB[n][0] = 32768 + row * 128 + ((lg ^ x) << 4);
        addrB[n][1] = 32768 + row * 128 + (((4 + lg) ^ x) << 4);
    }

    int baseA[4], ldsAo[4];
#pragma unroll
    for (int s = 0; s < 4; ++s) {
        int row = (wave * 4 + s) * 8 + (lane >> 3);
        int pos = posBase + row;
        int h = pos / 63;
        int w = pos - h * 63;
        int swzb = ((lane & 7) ^ (row & 7)) * 8;
        baseA[s] = (h * 65 + w) * 512 + swzb;
        ldsAo[s] = (wave * 4 + s) * 1024 + lane * 16;
    }
    int baseB[2], ldsBo[2];
#pragma unroll
    for (int s = 0; s < 2; ++s) {
        int row = (wave * 2 + s) * 8 + (lane >> 3);
        int swzb = ((lane & 7) ^ (row & 7)) * 8;
        baseB[s] = (coBase + row) * KK + swzb;
        ldsBo[s] = 32768 + (wave * 2 + s) * 1024 + lane * 16;
    }

    f32x4 acc[4][2];
#pragma unroll
    for (int m = 0; m < 4; ++m)
#pragma unroll
        for (int n = 0; n < 2; ++n) acc[m][n] = (f32x4){0.f, 0.f, 0.f, 0.f};

    const int kbeg = z * 1536;
    for (int step = 0; step < 24; ++step) {
        int k0 = kbeg + step * 64;
        int p = k0 >> 9;
        int ci0 = k0 & 511;
        int kh = p / 3;
        int kw = p - kh * 3;
        int dA = (kh * 65 + kw) * 512 + ci0;
#pragma unroll
        for (int s = 0; s < 4; ++s) {
            int so = baseA[s] + dA;
            gload16(FPH + so, lds + ldsAo[s]);
            gload16(FPL + so, lds + 16384 + ldsAo[s]);
        }
#pragma unroll
        for (int s = 0; s < 2; ++s) {
            int so = baseB[s] + k0;
            gload16(BHp + so, lds + ldsBo[s]);
            gload16(BLp + so, lds + 8192 + ldsBo[s]);
        }
        __syncthreads();
#pragma unroll
        for (int ks = 0; ks < 2; ++ks) {
            half8 aH[4], aL[4], bH[2], bL[2];
#pragma unroll
            for (int m = 0; m < 4; ++m) {
                aH[m] = *(const half8*)(lds + addrA[m][ks]);
                aL[m] = *(const half8*)(lds + 16384 + addrA[m][ks]);
            }
#pragma unroll
            for (int n = 0; n < 2; ++n) {
                bH[n] = *(const half8*)(lds + addrB[n][ks]);
                bL[n] = *(const half8*)(lds + 8192 + addrB[n][ks]);
            }
#pragma unroll
            for (int m = 0; m < 4; ++m)
#pragma unroll
                for (int n = 0; n < 2; ++n) {
                    acc[m][n] = __builtin_amdgcn_mfma_f32_16x16x32_f16(aH[m], bH[n], acc[m][n], 0, 0, 0);
                    acc[m][n] = __builtin_amdgcn_mfma_f32_16x16x32_f16(aH[m], bL[n], acc[m][n], 0, 0, 0);
                    acc[m][n] = __builtin_amdgcn_mfma_f32_16x16x32_f16(aL[m], bH[n], acc[m][n], 0, 0, 0);
                }
        }
        __syncthreads();
    }

#pragma unroll
    for (int m = 0; m < 4; ++m) {
        int pbase = posBase + wm * 64 + m * 16 + lg * 4;
        int co = coBase + wn * 32 + lr;
#pragma unroll
        for (int r = 0; r < 4; ++r) {
            int pos = pbase + r;
            if (pos < NPOS) {
                P[(size_t)pos * 512 + co]      = acc[m][0][r] * (1.f / 2048.f);
                P[(size_t)pos * 512 + co + 16] = acc[m][1][r] * (1.f / 2048.f);
            }
        }
    }
}

// 1x1 heads (fuses conv bias+ReLU over P0+P1+P2) + softmax-prob + decode + clip + key.
__global__ __launch_bounds__(256) void k_heads(const float* __restrict__ P0,
                                               const float* __restrict__ P1,
                                               const float* __restrict__ P2,
                                               const float* __restrict__ brpn,
                                               const float* __restrict__ wcls,
                                               const float* __restrict__ bcls,
                                               const float* __restrict__ wbbox,
                                               const float* __restrict__ bbbox,
                                               const float* __restrict__ anchors,
                                               float* __restrict__ proposals,
                                               unsigned long long* __restrict__ keys) {
    __shared__ float x[512];
    __shared__ float part[54][4];
    __shared__ float logit[54];
    int pos = blockIdx.x;
    int t = threadIdx.x;
    {
        size_t o = (size_t)pos * 512 + t;
        float v0 = P0[o] + P1[o] + P2[o] + brpn[t];
        float v1 = P0[o + 256] + P1[o + 256] + P2[o + 256] + brpn[t + 256];
        x[t] = v0 > 0.f ? v0 : 0.f;
        x[t + 256] = v1 > 0.f ? v1 : 0.f;
    }
    __syncthreads();
    if (t < 216) {
        int o = t >> 2, q = t & 3;
        const float* wr = (o < 18) ? (wcls + o * 512) : (wbbox + (o - 18) * 512);
        float s = 0.f;
        int base = q * 128;
#pragma unroll 4
        for (int k2 = 0; k2 < 128; ++k2) s += x[base + k2] * wr[base + k2];
        part[o][q] = s;
    }
    __syncthreads();
    if (t < 54) {
        float b = (t < 18) ? bcls[t] : bbbox[t - 18];
        logit[t] = part[t][0] + part[t][1] + part[t][2] + part[t][3] + b;
    }
    __syncthreads();
    if (t < 9) {
        int a = t;
        float bg = logit[a], fg = logit[9 + a];
        float score = 1.f / (1.f + expf(bg - fg));
        float dx = logit[18 + 4 * a], dy = logit[19 + 4 * a];
        float dw = logit[20 + 4 * a], dh = logit[21 + 4 * a];
        int idx = pos * 9 + a;
        float ax1 = anchors[idx * 4 + 0], ay1 = anchors[idx * 4 + 1];
        float ax2 = anchors[idx * 4 + 2], ay2 = anchors[idx * 4 + 3];
        float aw = ax2 - ax1 + 1.f, ah = ay2 - ay1 + 1.f;
        float cx = ax1 + 0.5f * aw, cy = ay1 + 0.5f * ah;
        float pcx = dx * aw + cx, pcy = dy * ah + cy;
        float pw = expf(dw) * aw, ph = expf(dh) * ah;
        float x1 = fminf(fmaxf(pcx - 0.5f * pw, 0.f), 999.f);
        float y1 = fminf(fmaxf(pcy - 0.5f * ph, 0.f), 599.f);
        float x2 = fminf(fmaxf(pcx + 0.5f * pw, 0.f), 999.f);
        float y2 = fminf(fmaxf(pcy + 0.5f * ph, 0.f), 599.f);
        proposals[idx * 4 + 0] = x1; proposals[idx * 4 + 1] = y1;
        proposals[idx * 4 + 2] = x2; proposals[idx * 4 + 3] = y2;
        union { float f; unsigned int i; } sv; sv.f = score;
        keys[idx] = (((unsigned long long)sv.i) << 32) |
                    (unsigned long long)(0xFFFFFFFFu - (unsigned)idx);
    }
}

__global__ __launch_bounds__(256) void k_rank_partial(const unsigned long long* __restrict__ keys,
                                                      unsigned int* __restrict__ rpart) {
    __shared__ unsigned long long kc[1024];
    int i = blockIdx.x * 256 + threadIdx.x;
    int q = blockIdx.y;
    unsigned long long myk = (i < NANCH) ? keys[i] : 0xFFFFFFFFFFFFFFFFull;
    int j0 = q * QLEN;
    int j1 = j0 + QLEN; if (j1 > NANCH) j1 = NANCH;
    unsigned int cnt = 0;
    for (int base = j0; base < j1; base += 1024) {
        int nload = j1 - base; if (nload > 1024) nload = 1024;
        __syncthreads();
        for (int u = threadIdx.x; u < 1024; u += 256)
            kc[u] = (base + u < j1) ? keys[base + u] : 0ull;
        __syncthreads();
        for (int u = 0; u < nload; ++u)
            cnt += (kc[u] > myk) ? 1u : 0u;
    }
    if (i < NANCH) rpart[i * NQ + q] = cnt;
}

// Ranks are a permutation of 0..NANCH-1 (keys unique via idx tiebreak), so all
// PRE slots get written -> no zero-init of sboxes needed.
__global__ void k_rank_scatter(const unsigned int* __restrict__ rpart,
                               const float* __restrict__ proposals,
                               float* __restrict__ sboxes) {
    int i = blockIdx.x * 256 + threadIdx.x;
    if (i >= NANCH) return;
    unsigned int r = 0;
#pragma unroll
    for (int q = 0; q < NQ; q++) r += rpart[i * NQ + q];
    if (r < PRE) {
        sboxes[r * 4 + 0] = proposals[i * 4 + 0];
        sboxes[r * 4 + 1] = proposals[i * 4 + 1];
        sboxes[r * 4 + 2] = proposals[i * 4 + 2];
        sboxes[r * 4 + 3] = proposals[i * 4 + 3];
    }
}

// IoU mask. Also packs the per-candidate diagonal 4-word slice into diag4.
// diag4 padding rows (6000..6143) are never selected by the scan (valid mask),
// so they need no zero-init.
__global__ __launch_bounds__(64) void k_nms_mask(const float* __restrict__ sboxes,
                                                 unsigned long long* __restrict__ mask,
                                                 unsigned long long* __restrict__ diag4) {
    __shared__ float bx[64][5];   // pad: breaks 8-way write bank conflict
    int ib = blockIdx.x, jb = blockIdx.y;
    int lane = threadIdx.x;
    int j = jb * 64 + lane;
    if (j < PRE) {
        bx[lane][0] = sboxes[j * 4 + 0]; bx[lane][1] = sboxes[j * 4 + 1];
        bx[lane][2] = sboxes[j * 4 + 2]; bx[lane][3] = sboxes[j * 4 + 3];
    } else {
        bx[lane][0] = 3e8f; bx[lane][1] = 3e8f; bx[lane][2] = 3e8f; bx[lane][3] = 3e8f;
    }
    __syncthreads();
    int i = ib * 64 + lane;
    if (i >= PRE) return;
    float x1 = sboxes[i * 4 + 0], y1 = sboxes[i * 4 + 1];
    float x2 = sboxes[i * 4 + 2], y2 = sboxes[i * 4 + 3];
    float ar = (x2 - x1 + 1.f) * (y2 - y1 + 1.f);
    unsigned long long bits = 0;
#pragma unroll 4
    for (int u = 0; u < 64; u++) {
        int j2 = jb * 64 + u;
        float iw = fminf(x2, bx[u][2]) - fmaxf(x1, bx[u][0]) + 1.f;
        float ih = fminf(y2, bx[u][3]) - fmaxf(y1, bx[u][1]) + 1.f;
        iw = fmaxf(iw, 0.f); ih = fmaxf(ih, 0.f);
        float inter = iw * ih;
        float arj = (bx[u][2] - bx[u][0] + 1.f) * (bx[u][3] - bx[u][1] + 1.f);
        float iou = inter / (ar + arj - inter);
        if (iou > 0.7f && j2 > i) bits |= (1ull << u);
    }
    mask[(size_t)i * NWORD + jb] = bits;
    if ((jb >> 2) == (ib >> 2)) diag4[(size_t)i * 4 + (jb & 3)] = bits;
}

// Greedy scan, 256-wide superblocks, counted-vmcnt pipeline (R9 decision loop:
// pure-VALU chain — measured faster than the SGPR-scalarized variant, whose
// VALU<->SALU domain crossings added wait-states).
// Decision chain per kept: ffs + ONE rl64 (current word); the 3 forward-word
// merges are deferred to phase end (pipelined readlanes, off-chain).
// FUSED roi-gather epilogue. Bit-identical greedy order.
#define NSB 24
#define SBW 256
#define NSLOT 20
__global__ __launch_bounds__(64) void k_nms_scan(const unsigned long long* __restrict__ mask,
                                                 const unsigned long long* __restrict__ diag4,
                                                 const float* __restrict__ sboxes,
                                                 float* __restrict__ outF) {
    __shared__ __align__(16) unsigned long long tile[2][SBW * 4];   // 2 x 8KB
    __shared__ __align__(16) char ldsrow[NSLOT * 1024];             // kept-row slots
    __shared__ int ldsk[POST];
    const int lane = threadIdx.x;
    const char* dg = (const char*)diag4;

    for (int c = 0; c < 8; ++c)
        gload16(dg + c * 1024 + (size_t)lane * 16, (char*)tile[0] + c * 1024);

    unsigned long long rem0 = 0, rem1 = 0;   // lane l owns words l and 64+l
    int nk = 0, npend = 0;

    for (int sb = 0; sb < NSB; ++sb) {
        if (sb + 1 < NSB) {
            const char* src = dg + (size_t)(sb + 1) * 8192;
            char* dst = (char*)tile[(sb + 1) & 1];
            for (int c = 0; c < 8; ++c)
                gload16(src + c * 1024 + (size_t)lane * 16, dst + c * 1024);
            asm volatile("s_waitcnt vmcnt(8)" ::: "memory");
        } else {
            asm volatile("s_waitcnt vmcnt(0)" ::: "memory");
        }
        __builtin_amdgcn_sched_barrier(0);

        for (int q = 0; q < npend; ++q) {
            const unsigned long long* lr = (const unsigned long long*)(ldsrow + q * 1024);
            rem0 |= lr[lane];
            if (lane < NWORD - 64) rem1 |= lr[64 + lane];
        }
        npend = 0;

        const unsigned long long* tl = tile[sb & 1];
        unsigned long long d[4][4];
#pragma unroll
        for (int q = 0; q < 4; ++q) {
            ulonglong2 e0 = *(const ulonglong2*)&tl[(q * 64 + lane) * 4];
            ulonglong2 e1 = *(const ulonglong2*)&tl[(q * 64 + lane) * 4 + 2];
            d[q][0] = e0.x; d[q][1] = e0.y; d[q][2] = e1.x; d[q][3] = e1.y;
        }

        const int w0 = 4 * sb;
        const int base = sb * SBW;
        unsigned long long rmw[4];
#pragma unroll
        for (int j = 0; j < 4; ++j) {
            int w = w0 + j;
            rmw[j] = (w < 64) ? rl64(rem0, w) : ((w < NWORD) ? rl64(rem1, w - 64) : ~0ull);
        }

#pragma unroll
        for (int p = 0; p < 4; ++p) {
            int w = w0 + p;
            if (w >= NWORD) break;
            const unsigned long long valid = (w == NWORD - 1) ? ((1ull << 48) - 1) : ~0ull;
            unsigned long long above = ~0ull;
            unsigned long long keptm = 0;
            for (;;) {
                unsigned long long a = ~rmw[p] & valid & above;
                if (!a) break;
                int u = (int)(__ffsll((long long)a) - 1);
                keptm |= 1ull << u;
                ++nk;
                if (nk == POST) break;
                rmw[p] |= rl64(d[p][p], u);          // only current word on the chain
                above = (u == 63) ? 0ull : (~0ull << (u + 1));
            }
            // deferred forward-word merges (pipelined, off the decision chain)
            {
                unsigned long long bits = keptm;
                while (bits) {
                    int u = (int)(__ffsll((long long)bits) - 1); bits &= bits - 1;
#pragma unroll
                    for (int j = p + 1; j < 4; ++j) rmw[j] |= rl64(d[p][j], u);
                }
            }
            // record keep indices + batched row-load issue (off-chain)
            unsigned long long bits = keptm;
            int nkb = nk - __builtin_popcountll(keptm);
            while (bits) {
                int u = (int)(__ffsll((long long)bits) - 1); bits &= bits - 1;
                int i = base + p * 64 + u;
                if (lane == 0) ldsk[nkb] = i;
                ++nkb;
                if (npend == NSLOT) {
                    asm volatile("s_waitcnt vmcnt(0)" ::: "memory");
                    __builtin_amdgcn_sched_barrier(0);
                    for (int q = 0; q < NSLOT; ++q) {
                        const unsigned long long* lr = (const unsigned long long*)(ldsrow + q * 1024);
                        rem0 |= lr[lane];
                        if (lane < NWORD - 64) rem1 |= lr[64 + lane];
                    }
                    npend = 0;
                }
                gload16((const char*)(mask + (size_t)i * NWORD) + (size_t)lane * 16,
                        ldsrow + npend * 1024);
                ++npend;
            }
            if (nk >= POST) goto done;
        }
    }
done:
    asm volatile("s_waitcnt vmcnt(0)" ::: "memory");
    // fused gather: boxes -> regs (all loads fenced before any store, since
    // header stores alias the sboxes scratch region inside d_out)
    float4 bx[5];
#pragma unroll
    for (int i = 0; i < 5; ++i) {
        int r = lane + i * 64;
        if (r < POST) {
            int ki = (r < nk) ? ldsk[r] : PRE - 1;
            bx[i] = *reinterpret_cast<const float4*>(sboxes + ki * 4);
        }
    }
    asm volatile("s_waitcnt vmcnt(0)" ::: "memory");
    __builtin_amdgcn_sched_barrier(0);
#pragma unroll
    for (int i = 0; i < 5; ++i) {
        int r = lane + i * 64;
        if (r < POST) {
#pragma unroll
            for (int cg = 0; cg < 8; ++cg)
                *reinterpret_cast<float4*>(outF + (size_t)(r * 512 + cg * 64) * 49) = bx[i];
        }
    }
}

// FAST crop: coalesced featT reads (lane=channel) + LDS-staged coalesced writes.
__global__ __launch_bounds__(256) void k_crop_fast(const float* __restrict__ featT,
                                                   float* out) {
    __shared__ float lds[4][49 * 65];
    int r = blockIdx.x;
    int w = threadIdx.x >> 6, lane = threadIdx.x & 63;
    int cg = blockIdx.y * 4 + w;
    int c = cg * 64 + lane;
    float* chunk = out + (size_t)(r * 512 + cg * 64) * 49;
    const float4 b = *reinterpret_cast<const float4*>(chunk);
    float x1 = b.x, y1 = b.y, x2 = b.z, y2 = b.w;
    float by1 = (y1 / 16.f) / 37.f, bx1 = (x1 / 16.f) / 62.f;
    float by2 = (y2 / 16.f) / 37.f, bx2 = (x2 / 16.f) / 62.f;
    float dyn = by2 - by1, dxn = bx2 - bx1;
    for (int e = 0; e < 49; ++e) {
        int oy = e / 7, ox = e - oy * 7;
        float vv[4];
#pragma unroll
        for (int dy = 0; dy < 2; ++dy) {
            int sy = 2 * oy + dy;
            float ty = (float)sy / 13.f;
            float ys = by1 * 37.f + (ty * dyn) * 37.f;
            float yf = floorf(ys);
            float wy = ys - yf;
            int y0  = (int)fminf(fmaxf(yf, 0.f), 37.f);
            int y1i = (int)fminf(fmaxf(yf + 1.f, 0.f), 37.f);
#pragma unroll
            for (int dxx = 0; dxx < 2; ++dxx) {
                int sx = 2 * ox + dxx;
                float tx = (float)sx / 13.f;
                float xs = bx1 * 62.f + (tx * dxn) * 62.f;
                float xf = floorf(xs);
                float wx = xs - xf;
                int x0  = (int)fminf(fmaxf(xf, 0.f), 62.f);
                int x1i = (int)fminf(fmaxf(xf + 1.f, 0.f), 62.f);
                float f00 = featT[(size_t)(y0 * 63 + x0) * 512 + c];
                float f01 = featT[(size_t)(y0 * 63 + x1i) * 512 + c];
                float f10 = featT[(size_t)(y1i * 63 + x0) * 512 + c];
                float f11 = featT[(size_t)(y1i * 63 + x1i) * 512 + c];
                vv[dy * 2 + dxx] = f00 * (1.f - wy) * (1.f - wx) + f01 * (1.f - wy) * wx +
                                   f10 * wy * (1.f - wx) + f11 * wy * wx;
            }
        }
        lds[w][e * 65 + lane] = fmaxf(fmaxf(vv[0], vv[1]), fmaxf(vv[2], vv[3]));
    }
    __syncthreads();
    for (int i = lane; i < 64 * 49; i += 64) {
        int cl = i / 49, e = i - cl * 49;
        chunk[i] = lds[w][e * 65 + cl];
    }
}

// SLOW fallback crop (reads NCHW net) — used only if ws too small
__global__ __launch_bounds__(64) void k_crop_slow(const float* __restrict__ net,
                                                  float* out) {
    int r = blockIdx.x, cg = blockIdx.y;
    int lane = threadIdx.x;
    int c = cg * 64 + lane;
    const float4 b = *reinterpret_cast<const float4*>(out + (size_t)(r * 512 + cg * 64) * 49);
    float x1 = b.x, y1 = b.y, x2 = b.z, y2 = b.w;
    float by1 = (y1 / 16.f) / 37.f, bx1 = (x1 / 16.f) / 62.f;
    float by2 = (y2 / 16.f) / 37.f, bx2 = (x2 / 16.f) / 62.f;
    float dyn = by2 - by1, dxn = bx2 - bx1;
    const float* fc = net + (size_t)c * NPOS;
    float* orow = out + ((size_t)r * 512 + c) * 49;
    for (int e = 0; e < 49; ++e) {
        int oy = e / 7, ox = e - oy * 7;
        float vv[4];
#pragma unroll
        for (int dy = 0; dy < 2; ++dy) {
            int sy = 2 * oy + dy;
            float ty = (float)sy / 13.f;
            float ys = by1 * 37.f + (ty * dyn) * 37.f;
            float yf = floorf(ys);
            float wy = ys - yf;
            int y0  = (int)fminf(fmaxf(yf, 0.f), 37.f);
            int y1i = (int)fminf(fmaxf(yf + 1.f, 0.f), 37.f);
#pragma unroll
            for (int dxx = 0; dxx < 2; ++dxx) {
                int sx = 2 * ox + dxx;
                float tx = (float)sx / 13.f;
                float xs = bx1 * 62.f + (tx * dxn) * 62.f;
                float xf = floorf(xs);
                float wx = xs - xf;
                int x0  = (int)fminf(fmaxf(xf, 0.f), 62.f);
                int x1i = (int)fminf(fmaxf(xf + 1.f, 0.f), 62.f);
                float f00 = fc[y0 * 63 + x0];
                float f01 = fc[y0 * 63 + x1i];
                float f10 = fc[y1i * 63 + x0];
                float f11 = fc[y1i * 63 + x1i];
                vv[dy * 2 + dxx] = f00 * (1.f - wy) * (1.f - wx) + f01 * (1.f - wy) * wx +
                                   f10 * wy * (1.f - wx) + f11 * wy * wx;
            }
        }
        orow[e] = fmaxf(fmaxf(vv[0], vv[1]), fmaxf(vv[2], vv[3]));
    }
}

extern "C" void kernel_launch(void* const* d_in, const int* in_sizes, int n_in,
                              void* d_out, int out_size, void* d_ws, size_t ws_size,
                              hipStream_t stream) {
    auto find = [&](int count, int fallback) {
        for (int i = 0; i < n_in; ++i) if (in_sizes[i] == count) return i;
        return fallback;
    };
    const float* net   = (const float*)d_in[find(NPOS * CIN, 0)];
    const float* wrpn  = (const float*)d_in[find(512 * KK, 1)];
    const float* brpn  = (const float*)d_in[find(512, 2)];
    const float* wcls  = (const float*)d_in[find(18 * 512, 3)];
    const float* bcls  = (const float*)d_in[find(18, 4)];
    const float* wbbox = (const float*)d_in[find(36 * 512, 5)];
    const float* bbbox = (const float*)d_in[find(36, 6)];
    const float* anch  = (const float*)d_in[find(NANCH * 4, 7)];

    char* ob = (char*)d_out;
    _Float16* BH             = (_Float16*)(ob + OFF_BH);
    _Float16* BL             = (_Float16*)(ob + OFF_BL);
    _Float16* FPH            = (_Float16*)(ob + OFF_FPH);
    _Float16* FPL            = (_Float16*)(ob + OFF_FPL);
    float* P0                = (float*)(ob + OFF_P0);
    float* P1                = (float*)(ob + OFF_P1);
    float* P2                = (float*)(ob + OFF_P2);
    unsigned long long* keys = (unsigned long long*)(ob + OFF_KEYS);
    float* proposals         = (float*)(ob + OFF_PROP);
    unsigned int* rpart      = (unsigned int*)(ob + OFF_RPART);
    float* sboxes            = (float*)(ob + OFF_SBOX);
    unsigned long long* diag4= (unsigned long long*)(ob + OFF_DIAG);
    unsigned long long* mask = (unsigned long long*)(ob + OFF_MASK);
    float* outF              = (float*)d_out;

    // featT in d_ws if it fits (survives the output-overwriting crop -> fast path).
    // Fallback: alias dead-until-conv P0 region (crop_slow reads net instead).
    const bool ws_ok = (ws_size >= (size_t)FEATT_BYTES);
    float* featT = ws_ok ? (float*)d_ws : (float*)(ob + OFF_P0);

    hipLaunchKernelGGL(k_prep_all, dim3(1200 + 9216 + 543), dim3(256), 0, stream,
                       net, wrpn, featT, FPH, FPL, BH, BL);
    hipLaunchKernelGGL(k_conv3_mfma, dim3(456), dim3(256), 0, stream, FPH, FPL, BH, BL, P0, P1, P2);
    hipLaunchKernelGGL(k_heads, dim3(NPOS), dim3(256), 0, stream, P0, P1, P2, brpn, wcls, bcls, wbbox, bbbox, anch, proposals, keys);
    hipLaunchKernelGGL(k_rank_partial, dim3(85, NQ), dim3(256), 0, stream, keys, rpart);
    hipLaunchKernelGGL(k_rank_scatter, dim3(85), dim3(256), 0, stream, rpart, proposals, sboxes);
    hipLaunchKernelGGL(k_nms_mask, dim3(NWORD, NWORD), dim3(64), 0, stream, sboxes, mask, diag4);
    hipLaunchKernelGGL(k_nms_scan, dim3(1), dim3(64), 0, stream, mask, diag4, sboxes, outF);
    if (ws_ok)
        hipLaunchKernelGGL(k_crop_fast, dim3(POST, 2), dim3(256), 0, stream, featT, outF);
    else
        hipLaunchKernelGGL(k_crop_slow, dim3(POST, 8), dim3(64), 0, stream, net, outF);
}